// Round 4
// baseline (239.369 us; speedup 1.0000x reference)
//
#include <hip/hip_runtime.h>
#include <utility>

#define EPS 1e-5f
typedef long long ll;
typedef float float4a __attribute__((ext_vector_type(4), aligned(4)));
typedef float float4v __attribute__((ext_vector_type(4)));

// ===================== compile-time path tables (RADIUS=5) =================
// Replicates reference _search_paths_dst(5): directions (0,1..4) then
// (y=1..4, x=-4..4, x^2+y^2<25); path pixels = box cells with
// (dx*y-dy*x)^2 < len_sq; dsts grouped by path length in first-seen order.
struct PathTables {
    int n;
    int dstY[34], dstX[34], plen[34];
    int py[34][11], px[34][11];
};
constexpr PathTables buildTables() {
    PathTables T{};
    int dirY[34] = {}, dirX[34] = {}; int nd = 0;
    for (int x = 1; x < 5; ++x) { dirY[nd] = 0; dirX[nd] = x; ++nd; }
    for (int y = 1; y < 5; ++y)
        for (int x = -4; x < 5; ++x)
            if (x * x + y * y < 25) { dirY[nd] = y; dirX[nd] = x; ++nd; }
    int L[34] = {}; int ppy[34][11] = {}, ppx[34][11] = {};
    for (int i = 0; i < nd; ++i) {
        int dy = dirY[i], dx = dirX[i], lsq = dy * dy + dx * dx, c = 0;
        int x0 = dx < 0 ? dx : 0, x1 = dx < 0 ? 0 : dx;
        for (int y = 0; y <= dy; ++y)
            for (int x = x0; x <= x1; ++x) {
                int num = dx * y - dy * x;
                if (num * num < lsq) { ppy[i][c] = y; ppx[i][c] = x; ++c; }
            }
        L[i] = c;
    }
    int lenOrder[16] = {}; int nl = 0;
    for (int i = 0; i < nd; ++i) {
        bool seen = false;
        for (int j = 0; j < nl; ++j) if (lenOrder[j] == L[i]) seen = true;
        if (!seen) lenOrder[nl++] = L[i];
    }
    int k = 0;
    for (int j = 0; j < nl; ++j)
        for (int i = 0; i < nd; ++i)
            if (L[i] == lenOrder[j]) {
                T.dstY[k] = dirY[i]; T.dstX[k] = dirX[i]; T.plen[k] = L[i];
                for (int l = 0; l < L[i]; ++l) { T.py[k][l] = ppy[i][l]; T.px[k][l] = ppx[i][l]; }
                ++k;
            }
    T.n = k;
    return T;
}
constexpr PathTables TAB = buildTables();

// host-side packed copy for device verification
struct HTab { int v[3 * 34 + 2 * 34 * 11]; };
constexpr HTab buildHTab() {
    HTab h{};
    for (int d = 0; d < 34; ++d) {
        h.v[d] = TAB.dstY[d]; h.v[34 + d] = TAB.dstX[d]; h.v[68 + d] = TAB.plen[d];
        for (int j = 0; j < 11; ++j) {
            h.v[102 + d * 11 + j] = TAB.py[d][j];
            h.v[102 + 374 + d * 11 + j] = TAB.px[d][j];
        }
    }
    return h;
}
constexpr HTab HT = buildHTab();

// ===================== setup: zero acc, extract offsets, verify ============
__global__ void setup_kernel(const int* __restrict__ path_idx,
                             const int* __restrict__ src_idx,
                             const int* __restrict__ dst_idx,
                             const float* __restrict__ dtv,
                             int n_dst, int Lmax, int n_pos, int HW, int host_ok,
                             double* __restrict__ acc, int* __restrict__ flag,
                             int* __restrict__ offs, int* __restrict__ doffs,
                             const int* __restrict__ htab) {
    int tid = threadIdx.x;
    if (tid < 8) acc[tid] = 0.0;
    if (tid == 0) *flag = 0;
    __syncthreads();
    int base0 = src_idx[0];
    for (int i = tid; i < n_dst * Lmax; i += 256)
        offs[i] = path_idx[(ll)i * n_pos] - base0;
    for (int i = tid; i < n_dst; i += 256)
        doffs[i] = dst_idx[(ll)i * n_pos] - base0;
    __syncthreads();
    if (!host_ok) { if (tid == 0) *flag = 1; return; }

    const int* tY = htab;        const int* tX = htab + 34;
    const int* tL = htab + 68;   const int* tPY = htab + 102;
    const int* tPX = htab + 102 + 374;
    int bad = 0;
    int W = doffs[1];                       // table says dst[1]=(1,0) => doffs[1]=W
    if (tid == 0 && (W < 12 || (W % 4) != 0)) bad = 1;
    if (tid < n_dst) {
        int d = tid;
        if (doffs[d] != tY[d] * W + tX[d]) bad = 1;
        if (dtv[d] != (float)tY[d] || dtv[n_dst + d] != (float)tX[d]) bad = 1;
        int L = tL[d];
        for (int l = 0; l < Lmax; ++l) {            // runtime path ⊆ table set
            int o = offs[d * Lmax + l]; int found = 0;
            for (int j = 0; j < L; ++j)
                if (o == tPY[d * 11 + j] * W + tPX[d * 11 + j]) found = 1;
            if (!found) bad = 1;
        }
        for (int j = 0; j < L; ++j) {               // table set ⊆ runtime path
            int o = tPY[d * 11 + j] * W + tPX[d * 11 + j]; int found = 0;
            for (int l = 0; l < Lmax; ++l)
                if (offs[d * Lmax + l] == o) found = 1;
            if (!found) bad = 1;
        }
    }
    int nvec = n_pos / 4;
    for (int v = tid; v < nvec; v += 256) {
        int b0 = src_idx[4 * v];
        if (b0 % 4) bad = 1;
        if (src_idx[4 * v + 1] != b0 + 1 || src_idx[4 * v + 2] != b0 + 2 ||
            src_idx[4 * v + 3] != b0 + 3) bad = 1;
        int col = b0 % W;
        if (col < 4 || col + 7 >= W) bad = 1;       // window cols in-bounds
        if (b0 + 4 * W + 7 >= HW) bad = 1;          // window rows in-bounds
    }
    if (bad) atomicOr(flag, 1);
}

// ===================== per-dst static compute ==============================
template<int DI, int... Ls>
__device__ __forceinline__ void path_max(const float (&ew)[5][12],
                                         float& m0, float& m1, float& m2, float& m3,
                                         std::integer_sequence<int, Ls...>) {
    ((m0 = fmaxf(m0, ew[TAB.py[DI][Ls]][TAB.px[DI][Ls] + 4]),
      m1 = fmaxf(m1, ew[TAB.py[DI][Ls]][TAB.px[DI][Ls] + 5]),
      m2 = fmaxf(m2, ew[TAB.py[DI][Ls]][TAB.px[DI][Ls] + 6]),
      m3 = fmaxf(m3, ew[TAB.py[DI][Ls]][TAB.px[DI][Ls] + 7])), ...);
}

template<int DI>
__device__ __forceinline__ void process_dst(
    const float (&ew)[5][12], const float (&ds0)[4], const float (&ds1)[4],
    const float* lbB, const float* lbF, const float* lbN, int n_pos,
    const float* dpb, int base, int W, int HW,
    float& s1, float& s2, float& s3, float& s4, float& s5,
    float& snb, float& snf, float& snn) {
    constexpr int DY = TAB.dstY[DI], DX = TAB.dstX[DI];
    float m0 = -1e30f, m1 = -1e30f, m2 = -1e30f, m3 = -1e30f;
    path_max<DI>(ew, m0, m1, m2, m3, std::make_integer_sequence<int, TAB.plen[DI]>{});
    float mm[4] = {fmaxf(m0, -80.f), fmaxf(m1, -80.f), fmaxf(m2, -80.f), fmaxf(m3, -80.f)};
    float pl[4], nl[4];
#pragma unroll
    for (int k = 0; k < 4; ++k) {
        float t = __expf(-mm[k]);          // sig = 1/(1+t)
        float u = 1.0f + t;
        float lu = __logf(u);
        pl[k] = lu - __logf(fmaf(EPS, u, t));     // -log(1-sig+eps)
        nl[k] = lu - __logf(fmaf(EPS, u, 1.0f));  // -log(sig+eps)
    }
    float4v vb = *(const float4v*)(lbB + DI * n_pos);
    float4v vf = *(const float4v*)(lbF + DI * n_pos);
    float4v vn = *(const float4v*)(lbN + DI * n_pos);
    const float* q = dpb + base + DY * W + DX;
    float4a q0v = *(const float4a*)q;
    float4a q1v = *(const float4a*)(q + HW);
#pragma unroll
    for (int k = 0; k < 4; ++k) {
        snb += vb[k]; snf += vf[k]; snn += vn[k];
        s1 = fmaf(vb[k], pl[k], s1);
        s2 = fmaf(vf[k], pl[k], s2);
        s3 = fmaf(vn[k], nl[k], s3);
        float q0 = ds0[k] - q0v[k];
        float q1 = ds1[k] - q1v[k];
        s4 = fmaf(vf[k], fabsf(q0 - (float)DY) + fabsf(q1 - (float)DX), s4);
        s5 = fmaf(vb[k], fabsf(q0) + fabsf(q1), s5);
    }
}

template<int PAR, int I>
struct DstChain {
    static __device__ __forceinline__ void run(
        const float (&ew)[5][12], const float (&ds0)[4], const float (&ds1)[4],
        const float* lbB, const float* lbF, const float* lbN, int n_pos,
        const float* dpb, int base, int W, int HW,
        float& s1, float& s2, float& s3, float& s4, float& s5,
        float& snb, float& snf, float& snn) {
        process_dst<PAR + 2 * I>(ew, ds0, ds1, lbB, lbF, lbN, n_pos, dpb, base, W, HW,
                                 s1, s2, s3, s4, s5, snb, snf, snn);
        if constexpr (PAR + 2 * (I + 1) < 34)
            DstChain<PAR, I + 1>::run(ew, ds0, ds1, lbB, lbF, lbN, n_pos, dpb, base, W, HW,
                                      s1, s2, s3, s4, s5, snb, snf, snn);
    }
};

// ===================== main kernel =========================================
// grid = (nvb, B, 2): x = vec-block of 64 threads (4 p each), y = batch,
// z = dst-parity. Single-wave blocks: no LDS, no __syncthreads.
__launch_bounds__(64, 2)
__global__ void loss_kernel(const float* __restrict__ edge, const float* __restrict__ dp,
                            const float* __restrict__ bgl, const float* __restrict__ fgl,
                            const float* __restrict__ ngl, const float* __restrict__ dtv,
                            const int* __restrict__ src_idx,
                            const int* __restrict__ offs, const int* __restrict__ doffs,
                            const int* __restrict__ flag,
                            int n_dst, int n_pos, int HW, int Lmax,
                            double* __restrict__ acc) {
    int tid = threadIdx.x;
    int vec = blockIdx.x * 64 + tid;
    int b   = blockIdx.y;
    int par = blockIdx.z;
    int p0  = vec * 4;
    float s1 = 0.f, s2 = 0.f, s3 = 0.f, s4 = 0.f, s5 = 0.f;
    float snb = 0.f, snf = 0.f, snn = 0.f;
    int bad = flag[0];

    if (p0 < n_pos) {
        const float* eb  = edge + (ll)b * HW;
        const float* dpb = dp + (ll)b * 2 * HW;
        ll labo = (ll)b * n_dst * n_pos + p0;
        const float* lbB = bgl + labo;
        const float* lbF = fgl + labo;
        const float* lbN = ngl + labo;

        if (!bad) {
            int W = doffs[1];
            int base = src_idx[p0];
            // edge window: rows 0..4, cols -4..7 (relative), all 16B-aligned
            float ew[5][12];
#pragma unroll
            for (int r = 0; r < 5; ++r) {
                const float* rp = eb + base + r * W - 4;
#pragma unroll
                for (int v = 0; v < 3; ++v) {
                    float4v t = *(const float4v*)(rp + v * 4);
#pragma unroll
                    for (int k = 0; k < 4; ++k) ew[r][v * 4 + k] = t[k];
                }
            }
            // dp src (row 0, cols 0..3), both channels
            float ds0[4], ds1[4];
            {
                float4v t0 = *(const float4v*)(dpb + base);
                float4v t1 = *(const float4v*)(dpb + HW + base);
#pragma unroll
                for (int k = 0; k < 4; ++k) { ds0[k] = t0[k]; ds1[k] = t1[k]; }
            }
            if (par == 0)
                DstChain<0, 0>::run(ew, ds0, ds1, lbB, lbF, lbN, n_pos, dpb, base, W, HW,
                                    s1, s2, s3, s4, s5, snb, snf, snn);
            else
                DstChain<1, 0>::run(ew, ds0, ds1, lbB, lbF, lbN, n_pos, dpb, base, W, HW,
                                    s1, s2, s3, s4, s5, snb, snf, snn);
        } else {
            // generic fallback: runtime offsets (slow, correctness safety net)
            for (int k = 0; k < 4; ++k) {
                int p = p0 + k; if (p >= n_pos) break;
                int bs = src_idx[p];
                for (int di = par; di < n_dst; di += 2) {
                    float m = -1e30f;
                    for (int l = 0; l < Lmax; ++l)
                        m = fmaxf(m, eb[bs + offs[di * Lmax + l]]);
                    m = fmaxf(m, -80.f);
                    float t = __expf(-m), u = 1.f + t, lu = __logf(u);
                    float plv = lu - __logf(fmaf(EPS, u, t));
                    float nlv = lu - __logf(fmaf(EPS, u, 1.f));
                    float vb = lbB[(ll)di * n_pos + k];
                    float vf = lbF[(ll)di * n_pos + k];
                    float vn = lbN[(ll)di * n_pos + k];
                    snb += vb; snf += vf; snn += vn;
                    s1 = fmaf(vb, plv, s1); s2 = fmaf(vf, plv, s2); s3 = fmaf(vn, nlv, s3);
                    int doff = doffs[di];
                    float q0 = dpb[bs] - dpb[bs + doff];
                    float q1 = dpb[HW + bs] - dpb[HW + bs + doff];
                    float d0 = dtv[di], d1 = dtv[n_dst + di];
                    s4 = fmaf(vf, fabsf(q0 - d0) + fabsf(q1 - d1), s4);
                    s5 = fmaf(vb, fabsf(q0) + fabsf(q1), s5);
                }
            }
        }
    }

    // single-wave reduction + f64 atomics
    float vals[8] = {s1, s2, s3, s4, s5, snb, snf, snn};
#pragma unroll
    for (int i = 0; i < 8; ++i) {
        float v = vals[i];
        for (int o = 32; o > 0; o >>= 1) v += __shfl_down(v, o);
        if (tid == 0) atomicAdd(&acc[i], (double)v);
    }
}

__global__ void finalize_kernel(const double* __restrict__ acc,
                                float* __restrict__ out) {
    double eps = 1e-5;
    double bg_pos = acc[0] / (acc[5] + eps);
    double fg_pos = acc[1] / (acc[6] + eps);
    double pos = 0.5 * bg_pos + 0.5 * fg_pos;
    double neg = acc[2] / (acc[7] + eps);
    double dfg = acc[3] / (2.0 * acc[6] + eps);
    double dbg = acc[4] / (2.0 * acc[5] + eps);
    out[0] = (float)(0.5 * (pos + neg) + 0.5 * (dfg + dbg));
}

// ===================== host ================================================
extern "C" void kernel_launch(void* const* d_in, const int* in_sizes, int n_in,
                              void* d_out, int out_size, void* d_ws, size_t ws_size,
                              hipStream_t stream) {
    const float* edge = (const float*)d_in[0];
    const float* dp   = (const float*)d_in[1];
    const float* bgl  = (const float*)d_in[2];
    const float* fgl  = (const float*)d_in[3];
    const float* ngl  = (const float*)d_in[4];
    const float* dtv  = (const float*)d_in[5];
    const int* path_idx = (const int*)d_in[6];
    const int* src_idx  = (const int*)d_in[7];
    const int* dst_idx  = (const int*)d_in[8];

    int n_pos = in_sizes[7];
    int n_dst = in_sizes[8] / n_pos;
    int Lmax  = in_sizes[6] / (n_dst * n_pos);
    int B     = in_sizes[2] / (n_dst * n_pos);
    int HW    = in_sizes[0] / B;

    int host_ok = (n_dst == 34 && Lmax == 11 && n_pos % 4 == 0 && n_pos >= 4);

    // ws layout: acc[8] (64B) | flag (4B) | pad | offs | doffs | htab
    double* acc  = (double*)d_ws;
    int* flag    = (int*)((char*)d_ws + 64);
    int* offs    = (int*)((char*)d_ws + 128);
    int* doffs   = offs + n_dst * Lmax;
    int* htab    = doffs + n_dst;
    // align htab to 16B
    htab = (int*)(((uintptr_t)htab + 15) & ~(uintptr_t)15);

    if (host_ok)
        hipMemcpyAsync(htab, HT.v, sizeof(HT.v), hipMemcpyHostToDevice, stream);

    setup_kernel<<<1, 256, 0, stream>>>(path_idx, src_idx, dst_idx, dtv,
                                        n_dst, Lmax, n_pos, HW, host_ok,
                                        acc, flag, offs, doffs, htab);

    int nvec = (n_pos + 3) / 4;
    int nvb  = (nvec + 63) / 64;
    loss_kernel<<<dim3(nvb, B, 2), 64, 0, stream>>>(
        edge, dp, bgl, fgl, ngl, dtv, src_idx, offs, doffs, flag,
        n_dst, n_pos, HW, Lmax, acc);

    finalize_kernel<<<1, 1, 0, stream>>>(acc, (float*)d_out);
}

// Round 5
// 66.944 us; speedup vs baseline: 3.5757x; 3.5757x over previous
//
#include <hip/hip_runtime.h>

#define EPS 1e-5f
typedef long long ll;
typedef float float4a __attribute__((ext_vector_type(4), aligned(4)));
typedef float float4v __attribute__((ext_vector_type(4)));

// ---------------- setup: extract constant offsets --------------------------
__global__ void setup_kernel(const int* __restrict__ path_idx,
                             const int* __restrict__ src_idx,
                             const int* __restrict__ dst_idx,
                             int n_dst, int Lmax, ll n_pos,
                             int* __restrict__ offs,
                             int* __restrict__ doffs,
                             double* __restrict__ acc) {
    int tid = threadIdx.x;
    if (tid < 8) acc[tid] = 0.0;
    int base0 = src_idx[0];
    int total = n_dst * Lmax;
    for (int i = tid; i < total; i += blockDim.x)
        offs[i] = path_idx[(ll)i * n_pos] - base0;
    for (int i = tid; i < n_dst; i += blockDim.x)
        doffs[i] = dst_idx[(ll)i * n_pos] - base0;
}

// ---------------- main fused kernel ----------------------------------------
// One (dst d, batch b, 4-pixel vec) unit per thread: 18 independent VMEM
// loads, no serial loop. Grid = n_dst * PB * B blocks of 256 threads.
template<int LMAX, bool USE_ATOMIC>
__launch_bounds__(256)
__global__ void loss_kernel(const float* __restrict__ edge,
                            const float* __restrict__ dp,
                            const float* __restrict__ bgl,
                            const float* __restrict__ fgl,
                            const float* __restrict__ ngl,
                            const float* __restrict__ dt,
                            const int*  __restrict__ src_idx,
                            const int*  __restrict__ offs,
                            const int*  __restrict__ doffs,
                            int n_dst, int n_pos, int HW, int B,
                            int PB, int Lrt,
                            float* __restrict__ partials, int nblk,
                            double* __restrict__ acc) {
    int bid = blockIdx.x;
    int d   = bid / (PB * B);
    int rem = bid - d * (PB * B);
    int pb  = rem / B;
    int b   = rem - pb * B;
    int tid = threadIdx.x;

    int off[LMAX];
#pragma unroll
    for (int l = 0; l < LMAX; ++l) {
        int li = (l < Lrt) ? l : (Lrt - 1);
        off[l] = offs[d * Lrt + li];
    }
    int   doff = doffs[d];
    float dt0  = dt[d];
    float dt1  = dt[n_dst + d];

    float s1 = 0.f, s2 = 0.f, s3 = 0.f, s4 = 0.f, s5 = 0.f;
    float snb = 0.f, snf = 0.f, snn = 0.f;

    int p0 = (pb * 256 + tid) * 4;
    if (p0 < n_pos) {
        int base = src_idx[p0];
        ll strideB = (ll)n_dst * n_pos;
        ll labo = (ll)b * strideB + (ll)d * n_pos + p0;

        // ---- issue the streaming loads first (labels + dp) ----
        float4v vb = *(const float4v*)(bgl + labo);
        float4v vf = *(const float4v*)(fgl + labo);
        float4v vn = *(const float4v*)(ngl + labo);

        const float* dpb = dp + (ll)b * 2 * HW + base;
        float4v a0 = *(const float4v*)(dpb);
        float4a c0 = *(const float4a*)(dpb + doff);
        float4v a1 = *(const float4v*)(dpb + HW);
        float4a c1 = *(const float4a*)(dpb + HW + doff);

        // ---- edge gathers + path max (sigmoid monotone) ----
        const float* ebase = edge + (ll)b * HW + base;
        float m0 = -1e30f, m1 = -1e30f, m2 = -1e30f, m3 = -1e30f;
#pragma unroll
        for (int l = 0; l < LMAX; ++l) {
            float4a v = *(const float4a*)(ebase + off[l]);
            m0 = fmaxf(m0, v[0]); m1 = fmaxf(m1, v[1]);
            m2 = fmaxf(m2, v[2]); m3 = fmaxf(m3, v[3]);
        }
        float mm[4] = {fmaxf(m0, -80.f), fmaxf(m1, -80.f),
                       fmaxf(m2, -80.f), fmaxf(m3, -80.f)};

        // sig = 1/(1+t), t = e^-m, u = 1+t.
        // posl = -log(1-sig+eps) = ln(u) - ln(t + eps*u)
        // negl = -log(sig+eps)   = ln(u) - ln(1 + eps*u)
#pragma unroll
        for (int k = 0; k < 4; ++k) {
            float t  = __expf(-mm[k]);
            float u  = 1.0f + t;
            float lu = __logf(u);
            float pl = lu - __logf(fmaf(EPS, u, t));
            float nl = lu - __logf(fmaf(EPS, u, 1.0f));

            snb += vb[k]; snf += vf[k]; snn += vn[k];
            s1 = fmaf(vb[k], pl, s1);
            s2 = fmaf(vf[k], pl, s2);
            s3 = fmaf(vn[k], nl, s3);

            float q0 = a0[k] - c0[k];
            float q1 = a1[k] - c1[k];
            s4 = fmaf(vf[k], fabsf(q0 - dt0) + fabsf(q1 - dt1), s4);
            s5 = fmaf(vb[k], fabsf(q0) + fabsf(q1), s5);
        }
    }

    // ---- block reduction: wave shfl -> LDS -> one write per accumulator ----
    float vals[8] = {s1, s2, s3, s4, s5, snb, snf, snn};
    __shared__ float red[4][8];
    int lane = tid & 63, wv = tid >> 6;
#pragma unroll
    for (int i = 0; i < 8; ++i) {
        float v = vals[i];
        for (int o = 32; o > 0; o >>= 1) v += __shfl_down(v, o);
        if (lane == 0) red[wv][i] = v;
    }
    __syncthreads();
    if (tid < 8) {
        float t = red[0][tid] + red[1][tid] + red[2][tid] + red[3][tid];
        if (USE_ATOMIC) atomicAdd(&acc[tid], (double)t);
        else            partials[(ll)tid * nblk + bid] = t;
    }
}

// ---------------- reduction of per-block partials --------------------------
__global__ void reduce_kernel(const float* __restrict__ partials, int nblk,
                              float* __restrict__ out) {
    int w = threadIdx.x >> 6, lane = threadIdx.x & 63;
    double s = 0.0;
    const float* src = partials + (ll)w * nblk;
    for (int i = lane; i < nblk; i += 64) s += (double)src[i];
    for (int o = 32; o > 0; o >>= 1) s += __shfl_down(s, o);
    __shared__ double sums[8];
    if (lane == 0) sums[w] = s;
    __syncthreads();
    if (threadIdx.x == 0) {
        double eps = 1e-5;
        double bg_pos = sums[0] / (sums[5] + eps);
        double fg_pos = sums[1] / (sums[6] + eps);
        double pos = 0.5 * bg_pos + 0.5 * fg_pos;
        double neg = sums[2] / (sums[7] + eps);
        double dfg = sums[3] / (2.0 * sums[6] + eps);
        double dbg = sums[4] / (2.0 * sums[5] + eps);
        out[0] = (float)(0.5 * (pos + neg) + 0.5 * (dfg + dbg));
    }
}

__global__ void finalize_atomic_kernel(const double* __restrict__ acc,
                                       float* __restrict__ out) {
    double eps = 1e-5;
    double bg_pos = acc[0] / (acc[5] + eps);
    double fg_pos = acc[1] / (acc[6] + eps);
    double pos = 0.5 * bg_pos + 0.5 * fg_pos;
    double neg = acc[2] / (acc[7] + eps);
    double dfg = acc[3] / (2.0 * acc[6] + eps);
    double dbg = acc[4] / (2.0 * acc[5] + eps);
    out[0] = (float)(0.5 * (pos + neg) + 0.5 * (dfg + dbg));
}

// ---------------- host ------------------------------------------------------
extern "C" void kernel_launch(void* const* d_in, const int* in_sizes, int n_in,
                              void* d_out, int out_size, void* d_ws, size_t ws_size,
                              hipStream_t stream) {
    const float* edge = (const float*)d_in[0];
    const float* dp   = (const float*)d_in[1];
    const float* bgl  = (const float*)d_in[2];
    const float* fgl  = (const float*)d_in[3];
    const float* ngl  = (const float*)d_in[4];
    const float* dt   = (const float*)d_in[5];
    const int* path_idx = (const int*)d_in[6];
    const int* src_idx  = (const int*)d_in[7];
    const int* dst_idx  = (const int*)d_in[8];

    int n_pos = in_sizes[7];
    int n_dst = in_sizes[8] / n_pos;
    int Lmax  = in_sizes[6] / (n_dst * n_pos);
    int B     = in_sizes[2] / (n_dst * n_pos);
    int HW    = in_sizes[0] / B;

    int PB = (n_pos / 4 + 255) / 256;
    int nblk = n_dst * PB * B;

    // workspace layout: partials | acc | offs | doffs
    size_t part_bytes = (size_t)8 * nblk * sizeof(float);
    size_t need = part_bytes + 64 + (size_t)n_dst * (Lmax + 1) * sizeof(int) + 64;
    bool use_atomic = (ws_size < need);

    float*  partials = (float*)d_ws;
    double* acc      = (double*)((char*)d_ws + (use_atomic ? 0 : part_bytes));
    int*    offs     = (int*)((char*)acc + 64);
    int*    doffs    = offs + (size_t)n_dst * Lmax;

    setup_kernel<<<1, 256, 0, stream>>>(path_idx, src_idx, dst_idx,
                                        n_dst, Lmax, n_pos, offs, doffs, acc);

    dim3 grid(n_dst * PB * B);

#define LAUNCH(LM, AT) loss_kernel<LM, AT><<<grid, 256, 0, stream>>>(   \
        edge, dp, bgl, fgl, ngl, dt, src_idx, offs, doffs,              \
        n_dst, n_pos, HW, B, PB, Lmax, partials, nblk, acc)

    if (use_atomic) {
        if      (Lmax <= 8)  LAUNCH(8,  true);
        else if (Lmax <= 11) LAUNCH(11, true);
        else if (Lmax <= 16) LAUNCH(16, true);
        else if (Lmax <= 24) LAUNCH(24, true);
        else                 LAUNCH(32, true);
        finalize_atomic_kernel<<<1, 1, 0, stream>>>(acc, (float*)d_out);
    } else {
        if      (Lmax <= 8)  LAUNCH(8,  false);
        else if (Lmax <= 11) LAUNCH(11, false);
        else if (Lmax <= 16) LAUNCH(16, false);
        else if (Lmax <= 24) LAUNCH(24, false);
        else                 LAUNCH(32, false);
        reduce_kernel<<<1, 512, 0, stream>>>(partials, nblk, (float*)d_out);
    }
#undef LAUNCH
}